// Round 17
// baseline (3269.007 us; speedup 1.0000x reference)
//
#include <hip/hip_runtime.h>

typedef unsigned int u32;
typedef unsigned short u16;
typedef short bf16x8 __attribute__((ext_vector_type(8)));
typedef float f32x4 __attribute__((ext_vector_type(4)));

#define DEV __device__ __forceinline__

// ---------- helpers ----------
DEV u16 f2bf(float f) {               // f32 -> bf16 bits, RNE
  u32 u = __builtin_bit_cast(u32, f);
  u += 0x7fffu + ((u >> 16) & 1u);
  return (u16)(u >> 16);
}
DEV float bf2f(u16 b) { u32 u = ((u32)b) << 16; return __builtin_bit_cast(float, u); }

DEV float dot2bf(float acc, u32 w, u32 h) {   // acc += w.lo*h.lo + w.hi*h.hi (bf16 pairs)
  asm("v_dot2_f32_bf16 %0, %1, %2, %0" : "+v"(acc) : "v"(w), "v"(h));
  return acc;
}

DEV void gload16(const void* g, void* l) {    // async global->LDS, 16B/lane
  __builtin_amdgcn_global_load_lds(
      (__attribute__((address_space(1))) void*)(void*)g,
      (__attribute__((address_space(3))) void*)l, 16, 0, 0);
}

// ---------- prep: W_hh -> bf16 pair-words, ALL 256 k-pairs to Wr ----------
#define PREG 256   // pair-words/thread in VGPR+AGPR (all of W)

__global__ void k_prep_whh(const float* __restrict__ w, u32* __restrict__ wr) {
  int idx = blockIdx.x * 256 + threadIdx.x;   // 131072 words: p = k-pair, j = column
  int p = idx >> 9, j = idx & 511;
  u32 word = (u32)f2bf(w[(2 * p) * 512 + j]) | ((u32)f2bf(w[(2 * p + 1) * 512 + j]) << 16);
  wr[p * 512 + j] = word;
}

// ---------- X = emb[x] @ W_xh + b_h  (f32, [4096][512]) ----------
__global__ __launch_bounds__(256) void k_embx(
    const int* __restrict__ x, const float* __restrict__ emb,
    const float* __restrict__ wxh, const float* __restrict__ bh,
    float* __restrict__ X) {
  __shared__ float sA[64][65];
  __shared__ __align__(16) float sB[64][68];
  int tid = threadIdx.x;
  int row0 = blockIdx.x * 64, col0 = blockIdx.y * 64;
  int tx = tid & 15, ty = tid >> 4;
  f32x4 acc[4] = {};
  for (int kc = 0; kc < 256; kc += 64) {
    __syncthreads();
#pragma unroll
    for (int i = 0; i < 4; ++i) {
      int f = i * 256 + tid;
      int r = f >> 4, c4 = (f & 15) * 4;
      int xr = x[row0 + r];
      float4 v = *(const float4*)&emb[(size_t)xr * 256 + kc + c4];
      sA[r][c4 + 0] = v.x; sA[r][c4 + 1] = v.y; sA[r][c4 + 2] = v.z; sA[r][c4 + 3] = v.w;
      float4 u = *(const float4*)&wxh[(size_t)(kc + r) * 512 + col0 + c4];
      *(float4*)&sB[r][c4] = u;
    }
    __syncthreads();
#pragma unroll
    for (int e = 0; e < 64; ++e) {
      f32x4 bv = *(const f32x4*)&sB[e][tx * 4];
      float a0 = sA[ty * 4 + 0][e], a1 = sA[ty * 4 + 1][e];
      float a2 = sA[ty * 4 + 2][e], a3 = sA[ty * 4 + 3][e];
      acc[0] += a0 * bv; acc[1] += a1 * bv; acc[2] += a2 * bv; acc[3] += a3 * bv;
    }
  }
  f32x4 bh4 = *(const f32x4*)&bh[col0 + tx * 4];
#pragma unroll
  for (int a = 0; a < 4; ++a) {
    f32x4 r = acc[a] + bh4;
    *(f32x4*)&X[(size_t)(row0 + ty * 4 + a) * 512 + col0 + tx * 4] = r;
  }
}

// ---------- RNN scan: R15 dot structure, W fully in regs; blocks>=8 convert fc_w ----------
// Accumulation order bit-identical to R10/R15 (absmax canary: must stay 0.00390625).
__global__ __launch_bounds__(512)
__attribute__((amdgpu_waves_per_eu(2, 2)))
void k_rnn(
    const u32* __restrict__ Wr, const float* __restrict__ X,
    u16* __restrict__ Hb16 /* comb base (bf16), write cols [0,512) of 1024 */,
    const float* __restrict__ fcw, u16* __restrict__ fcwb) {
  if (blockIdx.x >= 8) {                             // folded fc_w f32->bf16 conversion
    if (fcwb) {
      int i = (blockIdx.x - 8) * 512 + threadIdx.x;
      int stride = (gridDim.x - 8) * 512;
      for (; i < 8192000; i += stride) {
        float4 v = ((const float4*)fcw)[i];
        ushort4 r; r.x = f2bf(v.x); r.y = f2bf(v.y); r.z = f2bf(v.z); r.w = f2bf(v.w);
        ((ushort4*)fcwb)[i] = r;
      }
    }
    return;
  }
  __shared__ __align__(16) u32 hHI[2][256];          // h hi bf16 pairs, dbl-buffered
  __shared__ __align__(16) u32 hLO[2][256];          // h lo bf16 pairs
  int j = threadIdx.x;
  int b = blockIdx.x;
  u32 wreg[PREG];
#pragma unroll
  for (int p = 0; p < PREG; ++p) wreg[p] = Wr[p * 512 + j];
  if (j < 256) { hHI[0][j] = 0u; hLO[0][j] = 0u; }   // h0 = 0
  const float* Xb = X + (size_t)b * 512 * 512;
  u16* Hb = Hb16 + (size_t)b * 512 * 1024;
  __syncthreads();
  int cur = 0;
  float xv = Xb[j];                                  // t=0 prefetch
  for (int t = 0; t < 512; ++t) {
    int tn = t < 511 ? t + 1 : 511;
    float xnext = Xb[tn * 512 + j];                  // issue early; hides under dots
    float a0 = 0.f, a1 = 0.f, a2 = 0.f, a3 = 0.f;
    const u32* hbH = hHI[cur];
    const u32* hbL = hLO[cur];
#pragma unroll
    for (int c = 0; c < 64; ++c) {                   // all 64 groups from registers
      uint4 hH = *(const uint4*)&hbH[c * 4];
      uint4 hL = *(const uint4*)&hbL[c * 4];
      a0 = dot2bf(dot2bf(a0, wreg[c * 4 + 0], hH.x), wreg[c * 4 + 0], hL.x);
      a1 = dot2bf(dot2bf(a1, wreg[c * 4 + 1], hH.y), wreg[c * 4 + 1], hL.y);
      a2 = dot2bf(dot2bf(a2, wreg[c * 4 + 2], hH.z), wreg[c * 4 + 2], hL.z);
      a3 = dot2bf(dot2bf(a3, wreg[c * 4 + 3], hH.w), wreg[c * 4 + 3], hL.w);
    }
    float z = xv + ((a0 + a1) + (a2 + a3));          // b_h zeros, folded into X
    float ez = __expf(2.f * z);
    float h = 1.f - 2.f / (ez + 1.f);                // tanh(z)
    u16 hi = f2bf(h);
    u16 lo = f2bf(h - bf2f(hi));
    Hb[t * 1024 + j] = hi;                           // bf16 H for attention/FC
    ((u16*)hHI[cur ^ 1])[j] = hi;
    ((u16*)hLO[cur ^ 1])[j] = lo;
    __syncthreads();
    cur ^= 1;
    xv = xnext;
  }
}

// ---------- old bf16 MFMA GEMM (m97 structure) for attention + FC fallback ----------
template <int BF16OUT, int BIAS, int BF32B>
__global__ __launch_bounds__(256) void k_gemm_bt(
    const u16* __restrict__ A, int lda, long long aStr,
    const void* __restrict__ Bt_, int ldb, long long bStr,
    void* __restrict__ Cv, int ldc, long long cStr,
    int numMt, int numNt, int K, const float* __restrict__ bias) {
  __shared__ __align__(16) u16 lA[128 * 64];
  __shared__ __align__(16) u16 lB[128 * 64];
  int tid = threadIdx.x;
  int lane = tid & 63, wid = tid >> 6;
  int nwg = gridDim.x, wg = blockIdx.x;
  int q = nwg >> 3;
  int swz = (wg & 7) * q + (wg >> 3);
  int gm = numMt < 8 ? numMt : 8;
  int perg = gm * numNt;
  int grp = swz / perg;
  int rem = swz - grp * perg;
  int mt = grp * gm + rem % gm;
  int nt = rem / gm;
  int mrow = mt * 128, ncol = nt * 128;
  long long batch = blockIdx.y;
  A += batch * aStr;
  const u16* Bh = (const u16*)Bt_ + (BF32B ? 0 : batch * bStr);
  const float* Bf = (const float*)Bt_ + (BF32B ? batch * bStr : 0);
  float* Cf = (float*)Cv + batch * cStr;
  u16* Ch = (u16*)Cv + batch * cStr;

  f32x4 acc[4][4] = {};
  int wr = wid >> 1, wc = wid & 1;
  int lr = lane & 15, lk = (lane >> 4) * 8;

  for (int kt = 0; kt < K; kt += 64) {
    __syncthreads();
#pragma unroll
    for (int i = 0; i < 4; ++i) {
      int chunk = wid * 4 + i;
      int idx = chunk * 64 + lane;
      int r = idx >> 3, c = (idx & 7) * 8;
      gload16(&A[(size_t)(mrow + r) * lda + kt + c], &lA[chunk * 512]);
    }
    if constexpr (!BF32B) {
#pragma unroll
      for (int i = 0; i < 4; ++i) {
        int chunk = wid * 4 + i;
        int idx = chunk * 64 + lane;
        int r = idx >> 3, c = (idx & 7) * 8;
        gload16(&Bh[(size_t)(ncol + r) * ldb + kt + c], &lB[chunk * 512]);
      }
    } else {
#pragma unroll
      for (int u = 0; u < 8; ++u) {
        int flat = u * 1024 + tid * 4;
        int r = flat >> 6, c = flat & 63;
        float4 v = *(const float4*)&Bf[(size_t)(ncol + r) * ldb + kt + c];
        uint2 pk;
        pk.x = (u32)f2bf(v.x) | ((u32)f2bf(v.y) << 16);
        pk.y = (u32)f2bf(v.z) | ((u32)f2bf(v.w) << 16);
        *(uint2*)&lB[r * 64 + c] = pk;
      }
    }
    __syncthreads();
#pragma unroll
    for (int ks = 0; ks < 2; ++ks) {
      bf16x8 aF[4], bF[4];
#pragma unroll
      for (int mi = 0; mi < 4; ++mi)
        aF[mi] = *(const bf16x8*)&lA[(wr * 64 + mi * 16 + lr) * 64 + ks * 32 + lk];
#pragma unroll
      for (int ni = 0; ni < 4; ++ni)
        bF[ni] = *(const bf16x8*)&lB[(wc * 64 + ni * 16 + lr) * 64 + ks * 32 + lk];
#pragma unroll
      for (int mi = 0; mi < 4; ++mi)
#pragma unroll
        for (int ni = 0; ni < 4; ++ni)
          acc[mi][ni] = __builtin_amdgcn_mfma_f32_16x16x32_bf16(aF[mi], bF[ni], acc[mi][ni], 0, 0, 0);
    }
  }
  int rq = (lane >> 4) * 4;
#pragma unroll
  for (int ni = 0; ni < 4; ++ni) {
    int col = ncol + wc * 64 + ni * 16 + lr;
    float bv = BIAS ? bias[col] : 0.f;
#pragma unroll
    for (int mi = 0; mi < 4; ++mi) {
      int row = mrow + wr * 64 + mi * 16 + rq;
#pragma unroll
      for (int qq = 0; qq < 4; ++qq) {
        float v = acc[mi][ni][qq] + bv;
        if (BF16OUT) Ch[(size_t)(row + qq) * ldc + col] = f2bf(v);
        else         Cf[(size_t)(row + qq) * ldc + col] = v;
      }
    }
  }
}

// ---------- 8-phase 256x256 bf16 GEMM for FC: C = A @ B^T + bias ----------
DEV void stage_half(const u16* __restrict__ G, int ldg, int grow0, int kcol0,
                    u16* region, int w, int lane) {
#pragma unroll
  for (int jj = 0; jj < 2; ++jj) {
    int fb = jj * 512 + w * 64;                 // wave-uniform 16B-chunk base
    int f = fb + lane;
    int r = f >> 2, s = f & 3;
    int c = (s ^ ((r >> 1) & 3)) * 8;
    gload16(&G[(size_t)(grow0 + r) * ldg + kcol0 + c], region + (size_t)fb * 8);
  }
}
DEV bf16x8 lds_frag(const u16* region, int r, int lq) {
  return *(const bf16x8*)&region[r * 32 + ((lq ^ ((r >> 1) & 3)) * 8)];
}

__global__ __launch_bounds__(512, 2) void k_gemm8(
    const u16* __restrict__ A, int lda,
    const u16* __restrict__ B, int ldb,
    float* __restrict__ C, int ldc,
    int numMt, int numNt, int K, const float* __restrict__ bias) {
  __shared__ __align__(16) u16 lds8[65536];     // 128 KiB
  int tid = threadIdx.x;
  int lane = tid & 63, wid = tid >> 6;
  int w = wid, wm = wid >> 2, wn = wid & 3;
  int lr = lane & 15, lq = lane >> 4;
  int nwg = gridDim.x, wg = blockIdx.x;
  int qd = nwg >> 3;
  int swz = (wg & 7) * qd + (wg >> 3);
  int gm = numMt < 8 ? numMt : 8;
  int perg = gm * numNt;
  int grp = swz / perg;
  int rem = swz - grp * perg;
  int mt = grp * gm + rem % gm;
  int nt = rem / gm;
  int mrow = mt * 256, ncol = nt * 256;
  int NT = K >> 6;

#define REGION(buf, op, kh) (lds8 + (((buf) * 2 + (op)) * 2 + (kh)) * 8192)

  f32x4 acc[8][4];
#pragma unroll
  for (int mi = 0; mi < 8; ++mi)
#pragma unroll
    for (int ni = 0; ni < 4; ++ni) acc[mi][ni] = (f32x4){0.f, 0.f, 0.f, 0.f};

  stage_half(A, lda, mrow, 0,  REGION(0, 0, 0), w, lane);
  stage_half(B, ldb, ncol, 0,  REGION(0, 1, 0), w, lane);
  stage_half(A, lda, mrow, 32, REGION(0, 0, 1), w, lane);
  stage_half(B, ldb, ncol, 32, REGION(0, 1, 1), w, lane);
  stage_half(A, lda, mrow, 64, REGION(1, 0, 0), w, lane);
  stage_half(B, ldb, ncol, 64, REGION(1, 1, 0), w, lane);
  asm volatile("s_waitcnt vmcnt(4)" ::: "memory");
  __builtin_amdgcn_s_barrier();
  asm volatile("" ::: "memory");

  for (int T = 0; T < NT; ++T) {
    int buf = T & 1;
    int s12 = (T + 1 < NT), s34 = (T + 2 < NT);
#pragma unroll
    for (int ph = 0; ph < 4; ++ph) {
      int ch = ph & 1, ks = ph >> 1;
      const u16* Ar = REGION(buf, 0, ks);
      const u16* Br = REGION(buf, 1, ks);
      bf16x8 aF[8], bF[2];
#pragma unroll
      for (int mi = 0; mi < 8; ++mi)
        aF[mi] = lds_frag(Ar, wm * 128 + mi * 16 + lr, lq);
#pragma unroll
      for (int nl = 0; nl < 2; ++nl)
        bF[nl] = lds_frag(Br, wn * 64 + (ch * 2 + nl) * 16 + lr, lq);
      if (ph == 0) { if (s12) stage_half(A, lda, mrow, (T + 1) * 64 + 32, REGION(buf ^ 1, 0, 1), w, lane); }
      if (ph == 1) { if (s12) stage_half(B, ldb, ncol, (T + 1) * 64 + 32, REGION(buf ^ 1, 1, 1), w, lane); }
      if (ph == 2) { if (s34) stage_half(A, lda, mrow, (T + 2) * 64,      REGION(buf, 0, 0),     w, lane); }
      if (ph == 3) { if (s34) stage_half(B, ldb, ncol, (T + 2) * 64,      REGION(buf, 1, 0),     w, lane); }
      asm volatile("" ::: "memory");
      __builtin_amdgcn_s_barrier();
      asm volatile("s_waitcnt lgkmcnt(0)" ::: "memory");
      __builtin_amdgcn_sched_barrier(0);
      __builtin_amdgcn_s_setprio(1);
#pragma unroll
      for (int mi = 0; mi < 8; ++mi) {
        acc[mi][ch * 2 + 0] = __builtin_amdgcn_mfma_f32_16x16x32_bf16(aF[mi], bF[0], acc[mi][ch * 2 + 0], 0, 0, 0);
        acc[mi][ch * 2 + 1] = __builtin_amdgcn_mfma_f32_16x16x32_bf16(aF[mi], bF[1], acc[mi][ch * 2 + 1], 0, 0, 0);
      }
      __builtin_amdgcn_s_setprio(0);
      if (ph == 3) {
        if (T >= NT - 2) asm volatile("s_waitcnt vmcnt(0)" ::: "memory");
        else             asm volatile("s_waitcnt vmcnt(4)" ::: "memory");
      }
      asm volatile("" ::: "memory");
      __builtin_amdgcn_s_barrier();
      asm volatile("" ::: "memory");
    }
  }
#undef REGION

#pragma unroll
  for (int mi = 0; mi < 8; ++mi) {
    int row0 = mrow + wm * 128 + mi * 16 + lq * 4;
#pragma unroll
    for (int ni = 0; ni < 4; ++ni) {
      int col = ncol + wn * 64 + ni * 16 + lr;
      float bv = bias[col];
#pragma unroll
      for (int rg = 0; rg < 4; ++rg)
        C[(size_t)(row0 + rg) * ldc + col] = acc[mi][ni][rg] + bv;
    }
  }
}

// ---------- row softmax: S[4096][512] f32 -> P bf16 ----------
__global__ __launch_bounds__(256) void k_softmax(const float* __restrict__ S, u16* __restrict__ P) {
  int wid = threadIdx.x >> 6, lane = threadIdx.x & 63;
  int row = blockIdx.x * 4 + wid;
  const float* sr = S + (size_t)row * 512;
  f32x4 v0 = *(const f32x4*)&sr[lane * 4];
  f32x4 v1 = *(const f32x4*)&sr[256 + lane * 4];
  float m = fmaxf(fmaxf(fmaxf(v0.x, v0.y), fmaxf(v0.z, v0.w)),
                  fmaxf(fmaxf(v1.x, v1.y), fmaxf(v1.z, v1.w)));
#pragma unroll
  for (int o = 32; o; o >>= 1) m = fmaxf(m, __shfl_xor(m, o, 64));
  f32x4 e0, e1;
  e0.x = __expf(v0.x - m); e0.y = __expf(v0.y - m); e0.z = __expf(v0.z - m); e0.w = __expf(v0.w - m);
  e1.x = __expf(v1.x - m); e1.y = __expf(v1.y - m); e1.z = __expf(v1.z - m); e1.w = __expf(v1.w - m);
  float s = (e0.x + e0.y + e0.z + e0.w) + (e1.x + e1.y + e1.z + e1.w);
#pragma unroll
  for (int o = 32; o; o >>= 1) s += __shfl_xor(s, o, 64);
  float inv = 1.f / s;
  ushort4 o0, o1;
  o0.x = f2bf(e0.x * inv); o0.y = f2bf(e0.y * inv); o0.z = f2bf(e0.z * inv); o0.w = f2bf(e0.w * inv);
  o1.x = f2bf(e1.x * inv); o1.y = f2bf(e1.y * inv); o1.z = f2bf(e1.z * inv); o1.w = f2bf(e1.w * inv);
  *(ushort4*)&P[(size_t)row * 512 + lane * 4] = o0;
  *(ushort4*)&P[(size_t)row * 512 + 256 + lane * 4] = o1;
}

// ---------- HT[b][h][s] = H[b][s][h]  (H = comb cols [0,512), bf16) ----------
__global__ __launch_bounds__(256) void k_transpose(const u16* __restrict__ Hsrc, u16* __restrict__ HT) {
  __shared__ __align__(16) u16 tile[64][72];
  int b = blockIdx.z;
  int sb = blockIdx.x * 64, hb = blockIdx.y * 64;
  int tid = threadIdx.x;
#pragma unroll
  for (int i = 0; i < 4; ++i) {
    int f = i * 256 + tid; int r = f >> 4, c4 = (f & 15) * 4;
    ushort4 v = *(const ushort4*)&Hsrc[((size_t)(b * 512 + sb + r)) * 1024 + hb + c4];
    *(ushort4*)&tile[r][c4] = v;
  }
  __syncthreads();
#pragma unroll
  for (int i = 0; i < 4; ++i) {
    int f = i * 256 + tid; int h = f >> 4, s4 = (f & 15) * 4;
    ushort4 v;
    v.x = tile[s4 + 0][h]; v.y = tile[s4 + 1][h]; v.z = tile[s4 + 2][h]; v.w = tile[s4 + 3][h];
    *(ushort4*)&HT[((size_t)(b * 512 + hb + h)) * 512 + sb + s4] = v;
  }
}

// ---------- launch ----------
extern "C" void kernel_launch(void* const* d_in, const int* in_sizes, int n_in,
                              void* d_out, int out_size, void* d_ws, size_t ws_size,
                              hipStream_t stream) {
  const int*   x   = (const int*)d_in[0];
  const float* emb = (const float*)d_in[1];
  const float* wxh = (const float*)d_in[2];
  const float* whh = (const float*)d_in[3];
  const float* bh  = (const float*)d_in[4];
  const float* fcw = (const float*)d_in[5];
  const float* fcb = (const float*)d_in[6];
  float* out = (float*)d_out;

  // ws: Wr 512KB + comb(bf16) 8.39MB [+ fcwb 65.5MB if it fits]
  char* ws = (char*)d_ws;
  u32* Wr  = (u32*)ws;                         //    524,288 B (256 x 512 words)
  u16* comb = (u16*)(ws + 524288);             //  8,388,608 B  [4096][1024] bf16 (H | ctx)
  u16* fcwb = (u16*)(ws + 524288 + 8388608);   // 65,536,000 B  (optional)
  bool bigws = ws_size >= (size_t)(524288 + 8388608 + 65536000);
  // scratch in d_out (524 MB), all dead before FC overwrites it
  char* ob = (char*)d_out;
  float* X  = (float*)ob;                      //  8,388,608 B
  float* S  = (float*)(ob + 8388608);          //  8,388,608 B
  u16*   P  = (u16*)(ob + 16777216);           //  4,194,304 B
  u16*   HT = (u16*)(ob + 20971520);           //  4,194,304 B

  k_prep_whh<<<dim3(512), dim3(256), 0, stream>>>(whh, Wr);
  k_embx<<<dim3(64, 8), dim3(256), 0, stream>>>(x, emb, wxh, bh, X);
  // RNN on blocks 0-7; blocks 8+ convert fc_w on the otherwise-idle CUs
  k_rnn<<<dim3(bigws ? 1024 : 8), dim3(512), 0, stream>>>(
      Wr, X, comb, fcw, bigws ? fcwb : (u16*)nullptr);
  // scores = H @ H^T per batch -> S f32
  k_gemm_bt<0, 0, 0><<<dim3(16, 8), dim3(256), 0, stream>>>(
      comb, 1024, 512LL * 1024, comb, 1024, 512LL * 1024,
      (void*)S, 512, 512LL * 512, 4, 4, 512, (const float*)nullptr);
  k_softmax<<<dim3(1024), dim3(256), 0, stream>>>(S, P);
  k_transpose<<<dim3(8, 8, 8), dim3(256), 0, stream>>>(comb, HT);
  // ctx = P @ H -> comb cols [512,1024) bf16
  k_gemm_bt<1, 0, 0><<<dim3(16, 8), dim3(256), 0, stream>>>(
      P, 512, 512LL * 512, HT, 512, 512LL * 512,
      (void*)(comb + 512), 1024, 512LL * 1024, 4, 4, 512, (const float*)nullptr);
  // out = combined @ fc_w^T + fc_b
  if (bigws)
    k_gemm8<<<dim3(2000), dim3(512), 0, stream>>>(
        comb, 1024, fcwb, 1024, out, 32000, 16, 125, 1024, fcb);
  else
    k_gemm_bt<0, 1, 1><<<dim3(8000), dim3(256), 0, stream>>>(
        comb, 1024, 0LL, fcw, 1024, 0LL,
        (void*)out, 32000, 0LL, 32, 250, 1024, fcb);
}

// Round 18
// 1630.000 us; speedup vs baseline: 2.0055x; 2.0055x over previous
//
#include <hip/hip_runtime.h>

typedef unsigned int u32;
typedef unsigned short u16;
typedef short bf16x8 __attribute__((ext_vector_type(8)));
typedef float f32x4 __attribute__((ext_vector_type(4)));

#define DEV __device__ __forceinline__

// ---------- helpers ----------
DEV u16 f2bf(float f) {               // f32 -> bf16 bits, RNE
  u32 u = __builtin_bit_cast(u32, f);
  u += 0x7fffu + ((u >> 16) & 1u);
  return (u16)(u >> 16);
}
DEV float bf2f(u16 b) { u32 u = ((u32)b) << 16; return __builtin_bit_cast(float, u); }

DEV float dot2bf(float acc, u32 w, u32 h) {   // acc += w.lo*h.lo + w.hi*h.hi (bf16 pairs)
  asm("v_dot2_f32_bf16 %0, %1, %2, %0" : "+v"(acc) : "v"(w), "v"(h));
  return acc;
}

DEV void gload16(const void* g, void* l) {    // async global->LDS, 16B/lane
  __builtin_amdgcn_global_load_lds(
      (__attribute__((address_space(1))) void*)(void*)g,
      (__attribute__((address_space(3))) void*)l, 16, 0, 0);
}

// ---------- prep: fc_w f32 -> bf16 ----------
__global__ void k_prep_fcw(const float* __restrict__ w, u16* __restrict__ o, int n4) {
  int i = blockIdx.x * blockDim.x + threadIdx.x;
  int stride = gridDim.x * blockDim.x;
  for (; i < n4; i += stride) {
    float4 v = ((const float4*)w)[i];
    ushort4 r; r.x = f2bf(v.x); r.y = f2bf(v.y); r.z = f2bf(v.z); r.w = f2bf(v.w);
    ((ushort4*)o)[i] = r;
  }
}

// ---------- prep: W_hh -> bf16 pair-words; k-pairs<PREG to Wr, rest quad-packed to Wq ----------
#define PREG 184   // pair-words/thread in VGPRs (k-pairs 0..183)
#define PLQ  18    // quad-groups in LDS (k-pairs 184..255, 72 words as 18 uint4)

__global__ void k_prep_whh(const float* __restrict__ w, u32* __restrict__ wr, u32* __restrict__ wq) {
  int idx = blockIdx.x * 256 + threadIdx.x;   // 131072 words: p = k-pair, j = column
  int p = idx >> 9, j = idx & 511;
  u32 word = (u32)f2bf(w[(2 * p) * 512 + j]) | ((u32)f2bf(w[(2 * p + 1) * 512 + j]) << 16);
  if (p < PREG) wr[p * 512 + j] = word;
  else { int d = p - PREG; wq[((d >> 2) * 512 + j) * 4 + (d & 3)] = word; }
}

// ---------- X = emb[x] @ W_xh + b_h  (f32, [4096][512]) ----------
__global__ __launch_bounds__(256) void k_embx(
    const int* __restrict__ x, const float* __restrict__ emb,
    const float* __restrict__ wxh, const float* __restrict__ bh,
    float* __restrict__ X) {
  __shared__ float sA[64][65];
  __shared__ __align__(16) float sB[64][68];
  int tid = threadIdx.x;
  int row0 = blockIdx.x * 64, col0 = blockIdx.y * 64;
  int tx = tid & 15, ty = tid >> 4;
  f32x4 acc[4] = {};
  for (int kc = 0; kc < 256; kc += 64) {
    __syncthreads();
#pragma unroll
    for (int i = 0; i < 4; ++i) {
      int f = i * 256 + tid;
      int r = f >> 4, c4 = (f & 15) * 4;
      int xr = x[row0 + r];
      float4 v = *(const float4*)&emb[(size_t)xr * 256 + kc + c4];
      sA[r][c4 + 0] = v.x; sA[r][c4 + 1] = v.y; sA[r][c4 + 2] = v.z; sA[r][c4 + 3] = v.w;
      float4 u = *(const float4*)&wxh[(size_t)(kc + r) * 512 + col0 + c4];
      *(float4*)&sB[r][c4] = u;
    }
    __syncthreads();
#pragma unroll
    for (int e = 0; e < 64; ++e) {
      f32x4 bv = *(const f32x4*)&sB[e][tx * 4];
      float a0 = sA[ty * 4 + 0][e], a1 = sA[ty * 4 + 1][e];
      float a2 = sA[ty * 4 + 2][e], a3 = sA[ty * 4 + 3][e];
      acc[0] += a0 * bv; acc[1] += a1 * bv; acc[2] += a2 * bv; acc[3] += a3 * bv;
    }
  }
  f32x4 bh4 = *(const f32x4*)&bh[col0 + tx * 4];
#pragma unroll
  for (int a = 0; a < 4; ++a) {
    f32x4 r = acc[a] + bh4;
    *(f32x4*)&X[(size_t)(row0 + ty * 4 + a) * 512 + col0 + tx * 4] = r;
  }
}

// ---------- RNN scan (R15-exact, proven 1226us): hi+lo bf16 feedback ----------
__global__ __launch_bounds__(512)
__attribute__((amdgpu_waves_per_eu(2, 2)))
void k_rnn(
    const u32* __restrict__ Wr, const u32* __restrict__ Wq,
    const float* __restrict__ X,
    u16* __restrict__ Hb16 /* comb base (bf16), write cols [0,512) of 1024 */) {
  __shared__ __align__(16) u32 wl[PLQ * 512 * 4];   // 147456 B, [q][j][4]
  __shared__ __align__(16) u32 hHI[2][256];         // h hi bf16 pairs, dbl-buffered
  __shared__ __align__(16) u32 hLO[2][256];         // h lo bf16 pairs
  int j = threadIdx.x;
  int b = blockIdx.x;
  u32 wreg[PREG];
#pragma unroll
  for (int p = 0; p < PREG; ++p) wreg[p] = Wr[p * 512 + j];
#pragma unroll
  for (int q = 0; q < PLQ; ++q)
    *(uint4*)&wl[(q * 512 + j) * 4] = *(const uint4*)&Wq[(q * 512 + j) * 4];
  if (j < 256) { hHI[0][j] = 0u; hLO[0][j] = 0u; }  // h0 = 0
  const float* Xb = X + (size_t)b * 512 * 512;
  u16* Hb = Hb16 + (size_t)b * 512 * 1024;
  __syncthreads();
  int cur = 0;
  float xv = Xb[j];                                  // t=0 prefetch
  for (int t = 0; t < 512; ++t) {
    int tn = t < 511 ? t + 1 : 511;
    float xnext = Xb[tn * 512 + j];                  // issue early; hides under dots
    float a0 = 0.f, a1 = 0.f, a2 = 0.f, a3 = 0.f;
    const u32* hbH = hHI[cur];
    const u32* hbL = hLO[cur];
#pragma unroll
    for (int c = 0; c < PREG / 4; ++c) {             // 46 groups
      uint4 hH = *(const uint4*)&hbH[c * 4];
      uint4 hL = *(const uint4*)&hbL[c * 4];
      a0 = dot2bf(dot2bf(a0, wreg[c * 4 + 0], hH.x), wreg[c * 4 + 0], hL.x);
      a1 = dot2bf(dot2bf(a1, wreg[c * 4 + 1], hH.y), wreg[c * 4 + 1], hL.y);
      a2 = dot2bf(dot2bf(a2, wreg[c * 4 + 2], hH.z), wreg[c * 4 + 2], hL.z);
      a3 = dot2bf(dot2bf(a3, wreg[c * 4 + 3], hH.w), wreg[c * 4 + 3], hL.w);
    }
#pragma unroll
    for (int q = 0; q < PLQ; ++q) {                  // 18 groups from LDS (b128 reads)
      uint4 wv = *(const uint4*)&wl[(q * 512 + j) * 4];
      uint4 hH = *(const uint4*)&hbH[PREG + q * 4];
      uint4 hL = *(const uint4*)&hbL[PREG + q * 4];
      a0 = dot2bf(dot2bf(a0, wv.x, hH.x), wv.x, hL.x);
      a1 = dot2bf(dot2bf(a1, wv.y, hH.y), wv.y, hL.y);
      a2 = dot2bf(dot2bf(a2, wv.z, hH.z), wv.z, hL.z);
      a3 = dot2bf(dot2bf(a3, wv.w, hH.w), wv.w, hL.w);
    }
    float z = xv + ((a0 + a1) + (a2 + a3));          // b_h zeros, folded into X
    float ez = __expf(2.f * z);
    float h = 1.f - 2.f / (ez + 1.f);                // tanh(z)
    u16 hi = f2bf(h);
    u16 lo = f2bf(h - bf2f(hi));
    Hb[t * 1024 + j] = hi;                           // bf16 H for attention/FC
    ((u16*)hHI[cur ^ 1])[j] = hi;
    ((u16*)hLO[cur ^ 1])[j] = lo;
    __syncthreads();
    cur ^= 1;
    xv = xnext;
  }
}

// ---------- old bf16 MFMA GEMM (m97 structure) for attention + FC fallback ----------
template <int BF16OUT, int BIAS, int BF32B>
__global__ __launch_bounds__(256) void k_gemm_bt(
    const u16* __restrict__ A, int lda, long long aStr,
    const void* __restrict__ Bt_, int ldb, long long bStr,
    void* __restrict__ Cv, int ldc, long long cStr,
    int numMt, int numNt, int K, const float* __restrict__ bias) {
  __shared__ __align__(16) u16 lA[128 * 64];
  __shared__ __align__(16) u16 lB[128 * 64];
  int tid = threadIdx.x;
  int lane = tid & 63, wid = tid >> 6;
  int nwg = gridDim.x, wg = blockIdx.x;
  int q = nwg >> 3;
  int swz = (wg & 7) * q + (wg >> 3);
  int gm = numMt < 8 ? numMt : 8;
  int perg = gm * numNt;
  int grp = swz / perg;
  int rem = swz - grp * perg;
  int mt = grp * gm + rem % gm;
  int nt = rem / gm;
  int mrow = mt * 128, ncol = nt * 128;
  long long batch = blockIdx.y;
  A += batch * aStr;
  const u16* Bh = (const u16*)Bt_ + (BF32B ? 0 : batch * bStr);
  const float* Bf = (const float*)Bt_ + (BF32B ? batch * bStr : 0);
  float* Cf = (float*)Cv + batch * cStr;
  u16* Ch = (u16*)Cv + batch * cStr;

  f32x4 acc[4][4] = {};
  int wr = wid >> 1, wc = wid & 1;
  int lr = lane & 15, lk = (lane >> 4) * 8;

  for (int kt = 0; kt < K; kt += 64) {
    __syncthreads();
#pragma unroll
    for (int i = 0; i < 4; ++i) {
      int chunk = wid * 4 + i;
      int idx = chunk * 64 + lane;
      int r = idx >> 3, c = (idx & 7) * 8;
      gload16(&A[(size_t)(mrow + r) * lda + kt + c], &lA[chunk * 512]);
    }
    if constexpr (!BF32B) {
#pragma unroll
      for (int i = 0; i < 4; ++i) {
        int chunk = wid * 4 + i;
        int idx = chunk * 64 + lane;
        int r = idx >> 3, c = (idx & 7) * 8;
        gload16(&Bh[(size_t)(ncol + r) * ldb + kt + c], &lB[chunk * 512]);
      }
    } else {
#pragma unroll
      for (int u = 0; u < 8; ++u) {
        int flat = u * 1024 + tid * 4;
        int r = flat >> 6, c = flat & 63;
        float4 v = *(const float4*)&Bf[(size_t)(ncol + r) * ldb + kt + c];
        uint2 pk;
        pk.x = (u32)f2bf(v.x) | ((u32)f2bf(v.y) << 16);
        pk.y = (u32)f2bf(v.z) | ((u32)f2bf(v.w) << 16);
        *(uint2*)&lB[r * 64 + c] = pk;
      }
    }
    __syncthreads();
#pragma unroll
    for (int ks = 0; ks < 2; ++ks) {
      bf16x8 aF[4], bF[4];
#pragma unroll
      for (int mi = 0; mi < 4; ++mi)
        aF[mi] = *(const bf16x8*)&lA[(wr * 64 + mi * 16 + lr) * 64 + ks * 32 + lk];
#pragma unroll
      for (int ni = 0; ni < 4; ++ni)
        bF[ni] = *(const bf16x8*)&lB[(wc * 64 + ni * 16 + lr) * 64 + ks * 32 + lk];
#pragma unroll
      for (int mi = 0; mi < 4; ++mi)
#pragma unroll
        for (int ni = 0; ni < 4; ++ni)
          acc[mi][ni] = __builtin_amdgcn_mfma_f32_16x16x32_bf16(aF[mi], bF[ni], acc[mi][ni], 0, 0, 0);
    }
  }
  int rq = (lane >> 4) * 4;
#pragma unroll
  for (int ni = 0; ni < 4; ++ni) {
    int col = ncol + wc * 64 + ni * 16 + lr;
    float bv = BIAS ? bias[col] : 0.f;
#pragma unroll
    for (int mi = 0; mi < 4; ++mi) {
      int row = mrow + wr * 64 + mi * 16 + rq;
#pragma unroll
      for (int qq = 0; qq < 4; ++qq) {
        float v = acc[mi][ni][qq] + bv;
        if (BF16OUT) Ch[(size_t)(row + qq) * ldc + col] = f2bf(v);
        else         Cf[(size_t)(row + qq) * ldc + col] = v;
      }
    }
  }
}

// ---------- 8-phase 256x256 bf16 GEMM for FC: C = A @ B^T + bias ----------
// aF[8] hoisted: loaded only when ks changes (ph0/ph2) -> 24 ds_read_b128/tile vs 40.
DEV void stage_half(const u16* __restrict__ G, int ldg, int grow0, int kcol0,
                    u16* region, int w, int lane) {
#pragma unroll
  for (int jj = 0; jj < 2; ++jj) {
    int fb = jj * 512 + w * 64;                 // wave-uniform 16B-chunk base
    int f = fb + lane;
    int r = f >> 2, s = f & 3;
    int c = (s ^ ((r >> 1) & 3)) * 8;
    gload16(&G[(size_t)(grow0 + r) * ldg + kcol0 + c], region + (size_t)fb * 8);
  }
}
DEV bf16x8 lds_frag(const u16* region, int r, int lq) {
  return *(const bf16x8*)&region[r * 32 + ((lq ^ ((r >> 1) & 3)) * 8)];
}

__global__ __launch_bounds__(512, 2) void k_gemm8(
    const u16* __restrict__ A, int lda,
    const u16* __restrict__ B, int ldb,
    float* __restrict__ C, int ldc,
    int numMt, int numNt, int K, const float* __restrict__ bias) {
  __shared__ __align__(16) u16 lds8[65536];     // 128 KiB
  int tid = threadIdx.x;
  int lane = tid & 63, wid = tid >> 6;
  int w = wid, wm = wid >> 2, wn = wid & 3;
  int lr = lane & 15, lq = lane >> 4;
  int nwg = gridDim.x, wg = blockIdx.x;
  int qd = nwg >> 3;
  int swz = (wg & 7) * qd + (wg >> 3);
  int gm = numMt < 8 ? numMt : 8;
  int perg = gm * numNt;
  int grp = swz / perg;
  int rem = swz - grp * perg;
  int mt = grp * gm + rem % gm;
  int nt = rem / gm;
  int mrow = mt * 256, ncol = nt * 256;
  int NT = K >> 6;

#define REGION(buf, op, kh) (lds8 + (((buf) * 2 + (op)) * 2 + (kh)) * 8192)

  f32x4 acc[8][4];
#pragma unroll
  for (int mi = 0; mi < 8; ++mi)
#pragma unroll
    for (int ni = 0; ni < 4; ++ni) acc[mi][ni] = (f32x4){0.f, 0.f, 0.f, 0.f};

  stage_half(A, lda, mrow, 0,  REGION(0, 0, 0), w, lane);
  stage_half(B, ldb, ncol, 0,  REGION(0, 1, 0), w, lane);
  stage_half(A, lda, mrow, 32, REGION(0, 0, 1), w, lane);
  stage_half(B, ldb, ncol, 32, REGION(0, 1, 1), w, lane);
  stage_half(A, lda, mrow, 64, REGION(1, 0, 0), w, lane);
  stage_half(B, ldb, ncol, 64, REGION(1, 1, 0), w, lane);
  asm volatile("s_waitcnt vmcnt(4)" ::: "memory");
  __builtin_amdgcn_s_barrier();
  asm volatile("" ::: "memory");

  for (int T = 0; T < NT; ++T) {
    int buf = T & 1;
    int s12 = (T + 1 < NT), s34 = (T + 2 < NT);
    bf16x8 aF[8];
#pragma unroll
    for (int ph = 0; ph < 4; ++ph) {
      int ch = ph & 1, ks = ph >> 1;
      const u16* Ar = REGION(buf, 0, ks);
      const u16* Br = REGION(buf, 1, ks);
      if (ch == 0) {                          // aF shared by both ch-phases of this ks
#pragma unroll
        for (int mi = 0; mi < 8; ++mi)
          aF[mi] = lds_frag(Ar, wm * 128 + mi * 16 + lr, lq);
      }
      bf16x8 bF[2];
#pragma unroll
      for (int nl = 0; nl < 2; ++nl)
        bF[nl] = lds_frag(Br, wn * 64 + (ch * 2 + nl) * 16 + lr, lq);
      if (ph == 0) { if (s12) stage_half(A, lda, mrow, (T + 1) * 64 + 32, REGION(buf ^ 1, 0, 1), w, lane); }
      if (ph == 1) { if (s12) stage_half(B, ldb, ncol, (T + 1) * 64 + 32, REGION(buf ^ 1, 1, 1), w, lane); }
      if (ph == 2) { if (s34) stage_half(A, lda, mrow, (T + 2) * 64,      REGION(buf, 0, 0),     w, lane); }
      if (ph == 3) { if (s34) stage_half(B, ldb, ncol, (T + 2) * 64,      REGION(buf, 1, 0),     w, lane); }
      asm volatile("" ::: "memory");
      __builtin_amdgcn_s_barrier();
      asm volatile("s_waitcnt lgkmcnt(0)" ::: "memory");
      __builtin_amdgcn_sched_barrier(0);
      __builtin_amdgcn_s_setprio(1);
#pragma unroll
      for (int mi = 0; mi < 8; ++mi) {
        acc[mi][ch * 2 + 0] = __builtin_amdgcn_mfma_f32_16x16x32_bf16(aF[mi], bF[0], acc[mi][ch * 2 + 0], 0, 0, 0);
        acc[mi][ch * 2 + 1] = __builtin_amdgcn_mfma_f32_16x16x32_bf16(aF[mi], bF[1], acc[mi][ch * 2 + 1], 0, 0, 0);
      }
      __builtin_amdgcn_s_setprio(0);
      if (ph == 3) {
        if (T >= NT - 2) asm volatile("s_waitcnt vmcnt(0)" ::: "memory");
        else             asm volatile("s_waitcnt vmcnt(4)" ::: "memory");
      }
      asm volatile("" ::: "memory");
      __builtin_amdgcn_s_barrier();
      asm volatile("" ::: "memory");
    }
  }
#undef REGION

#pragma unroll
  for (int mi = 0; mi < 8; ++mi) {
    int row0 = mrow + wm * 128 + mi * 16 + lq * 4;
#pragma unroll
    for (int ni = 0; ni < 4; ++ni) {
      int col = ncol + wn * 64 + ni * 16 + lr;
      float bv = bias[col];
#pragma unroll
      for (int rg = 0; rg < 4; ++rg)
        C[(size_t)(row0 + rg) * ldc + col] = acc[mi][ni][rg] + bv;
    }
  }
}

// ---------- row softmax: S[4096][512] f32 -> P bf16 ----------
__global__ __launch_bounds__(256) void k_softmax(const float* __restrict__ S, u16* __restrict__ P) {
  int wid = threadIdx.x >> 6, lane = threadIdx.x & 63;
  int row = blockIdx.x * 4 + wid;
  const float* sr = S + (size_t)row * 512;
  f32x4 v0 = *(const f32x4*)&sr[lane * 4];
  f32x4 v1 = *(const f32x4*)&sr[256 + lane * 4];
  float m = fmaxf(fmaxf(fmaxf(v0.x, v0.y), fmaxf(v0.z, v0.w)),
                  fmaxf(fmaxf(v1.x, v1.y), fmaxf(v1.z, v1.w)));
#pragma unroll
  for (int o = 32; o; o >>= 1) m = fmaxf(m, __shfl_xor(m, o, 64));
  f32x4 e0, e1;
  e0.x = __expf(v0.x - m); e0.y = __expf(v0.y - m); e0.z = __expf(v0.z - m); e0.w = __expf(v0.w - m);
  e1.x = __expf(v1.x - m); e1.y = __expf(v1.y - m); e1.z = __expf(v1.z - m); e1.w = __expf(v1.w - m);
  float s = (e0.x + e0.y + e0.z + e0.w) + (e1.x + e1.y + e1.z + e1.w);
#pragma unroll
  for (int o = 32; o; o >>= 1) s += __shfl_xor(s, o, 64);
  float inv = 1.f / s;
  ushort4 o0, o1;
  o0.x = f2bf(e0.x * inv); o0.y = f2bf(e0.y * inv); o0.z = f2bf(e0.z * inv); o0.w = f2bf(e0.w * inv);
  o1.x = f2bf(e1.x * inv); o1.y = f2bf(e1.y * inv); o1.z = f2bf(e1.z * inv); o1.w = f2bf(e1.w * inv);
  *(ushort4*)&P[(size_t)row * 512 + lane * 4] = o0;
  *(ushort4*)&P[(size_t)row * 512 + 256 + lane * 4] = o1;
}

// ---------- HT[b][h][s] = H[b][s][h]  (H = comb cols [0,512), bf16) ----------
__global__ __launch_bounds__(256) void k_transpose(const u16* __restrict__ Hsrc, u16* __restrict__ HT) {
  __shared__ __align__(16) u16 tile[64][72];
  int b = blockIdx.z;
  int sb = blockIdx.x * 64, hb = blockIdx.y * 64;
  int tid = threadIdx.x;
#pragma unroll
  for (int i = 0; i < 4; ++i) {
    int f = i * 256 + tid; int r = f >> 4, c4 = (f & 15) * 4;
    ushort4 v = *(const ushort4*)&Hsrc[((size_t)(b * 512 + sb + r)) * 1024 + hb + c4];
    *(ushort4*)&tile[r][c4] = v;
  }
  __syncthreads();
#pragma unroll
  for (int i = 0; i < 4; ++i) {
    int f = i * 256 + tid; int h = f >> 4, s4 = (f & 15) * 4;
    ushort4 v;
    v.x = tile[s4 + 0][h]; v.y = tile[s4 + 1][h]; v.z = tile[s4 + 2][h]; v.w = tile[s4 + 3][h];
    *(ushort4*)&HT[((size_t)(b * 512 + hb + h)) * 512 + sb + s4] = v;
  }
}

// ---------- launch ----------
extern "C" void kernel_launch(void* const* d_in, const int* in_sizes, int n_in,
                              void* d_out, int out_size, void* d_ws, size_t ws_size,
                              hipStream_t stream) {
  const int*   x   = (const int*)d_in[0];
  const float* emb = (const float*)d_in[1];
  const float* wxh = (const float*)d_in[2];
  const float* whh = (const float*)d_in[3];
  const float* bh  = (const float*)d_in[4];
  const float* fcw = (const float*)d_in[5];
  const float* fcb = (const float*)d_in[6];
  float* out = (float*)d_out;

  // ws: Wr 368KB + Wq 144KB (=0.5MB) + comb(bf16) 8.39MB [+ fcwb 65.5MB if it fits]
  char* ws = (char*)d_ws;
  u32* Wr  = (u32*)ws;                         //    376,832 B (184 x 512 words)
  u32* Wq  = (u32*)(ws + 376832);              //    147,456 B (18 quads x 512 x 4)
  u16* comb = (u16*)(ws + 524288);             //  8,388,608 B  [4096][1024] bf16 (H | ctx)
  u16* fcwb = (u16*)(ws + 524288 + 8388608);   // 65,536,000 B  (optional)
  bool bigws = ws_size >= (size_t)(524288 + 8388608 + 65536000);
  // scratch in d_out (524 MB), all dead before FC overwrites it
  char* ob = (char*)d_out;
  float* X  = (float*)ob;                      //  8,388,608 B
  float* S  = (float*)(ob + 8388608);          //  8,388,608 B
  u16*   P  = (u16*)(ob + 16777216);           //  4,194,304 B
  u16*   HT = (u16*)(ob + 20971520);           //  4,194,304 B

  k_prep_whh<<<dim3(512), dim3(256), 0, stream>>>(whh, Wr, Wq);
  k_embx<<<dim3(64, 8), dim3(256), 0, stream>>>(x, emb, wxh, bh, X);
  if (bigws)
    k_prep_fcw<<<dim3(2048), dim3(256), 0, stream>>>(fcw, fcwb, 8192000);
  k_rnn<<<dim3(8), dim3(512), 0, stream>>>(Wr, Wq, X, comb);
  // scores = H @ H^T per batch -> S f32
  k_gemm_bt<0, 0, 0><<<dim3(16, 8), dim3(256), 0, stream>>>(
      comb, 1024, 512LL * 1024, comb, 1024, 512LL * 1024,
      (void*)S, 512, 512LL * 512, 4, 4, 512, (const float*)nullptr);
  k_softmax<<<dim3(1024), dim3(256), 0, stream>>>(S, P);
  k_transpose<<<dim3(8, 8, 8), dim3(256), 0, stream>>>(comb, HT);
  // ctx = P @ H -> comb cols [512,1024) bf16
  k_gemm_bt<1, 0, 0><<<dim3(16, 8), dim3(256), 0, stream>>>(
      P, 512, 512LL * 512, HT, 512, 512LL * 512,
      (void*)(comb + 512), 1024, 512LL * 1024, 4, 4, 512, (const float*)nullptr);
  // out = combined @ fc_w^T + fc_b
  if (bigws)
    k_gemm8<<<dim3(2000), dim3(512), 0, stream>>>(
        comb, 1024, fcwb, 1024, out, 32000, 16, 125, 1024, fcb);
  else
    k_gemm_bt<0, 1, 1><<<dim3(8000), dim3(256), 0, stream>>>(
        comb, 1024, 0LL, fcw, 1024, 0LL,
        (void*)out, 32000, 0LL, 32, 250, 1024, fcb);
}